// Round 13
// baseline (112.573 us; speedup 1.0000x reference)
//
#include <hip/hip_runtime.h>
#include <hip/hip_bf16.h>
#include <stdint.h>

#define DEVI __device__ __forceinline__

typedef __attribute__((ext_vector_type(8))) short short8;
typedef __attribute__((ext_vector_type(4))) short short4v;
typedef __attribute__((ext_vector_type(4))) float floatx4;

DEVI ushort f2bf(float f) {
  union { float f; uint32_t u; } v; v.f = f;
  uint32_t u = v.u;
  uint32_t r = (u + 0x7FFFu + ((u >> 16) & 1u)) >> 16;
  return (ushort)r;
}
DEVI ushort f2bf_fast(float f) {
  union { float f; uint32_t u; } v; v.f = f;
  return (ushort)((v.u + 0x8000u) >> 16);
}
DEVI float bf2f(ushort h) {
  union { uint32_t u; float f; } v; v.u = ((uint32_t)h) << 16;
  return v.f;
}
DEVI void gld_lds16(const void* g, void* l) {
  __builtin_amdgcn_global_load_lds(
      (const __attribute__((address_space(1))) unsigned int*)g,
      (__attribute__((address_space(3))) unsigned int*)l, 16, 0, 0);
}

// ------- fused cast fp32 -> bf16 (x, qkv_w, proj_w) + RoPE table -------
__global__ __launch_bounds__(256, 4) void cast_all(
    const float* __restrict__ x, const float* __restrict__ w1,
    const float* __restrict__ w2, ushort* __restrict__ xb,
    ushort* __restrict__ w1b, ushort* __restrict__ w2b,
    float2* __restrict__ tab) {
  const int N1 = 4096 * 1024, N2 = 3072 * 1024, N3 = 1024 * 1024;
  int id = blockIdx.x * 256 + threadIdx.x;
  if (id < 32768) {  // RoPE cos/sin table: 1024 positions x 32 freq pairs
    int j = id & 31, n = id >> 5;
    float inv = powf(10000.0f, -(float)(2 * j) / 64.0f);
    float fr = (float)n * inv;
    tab[id] = make_float2(cosf(fr), sinf(fr));
  }
  int i = id * 4;
  const int total = N1 + N2 + N3;
  int stride = gridDim.x * 256 * 4;
  for (; i < total; i += stride) {
    const float* src; ushort* dst; int off;
    if (i < N1) { src = x; dst = xb; off = i; }
    else if (i < N1 + N2) { src = w1; dst = w1b; off = i - N1; }
    else { src = w2; dst = w2b; off = i - N1 - N2; }
    float4 v = *(const float4*)(src + off);
    ushort4 o;
    o.x = f2bf(v.x); o.y = f2bf(v.y); o.z = f2bf(v.z); o.w = f2bf(v.w);
    *(ushort4*)(dst + off) = o;
  }
}

// ---------------- GEMM1: qkv = x @ W^T + b, fused RoPE + scatter ----------
// r11-proven 2-phase dbuf + conflict-free swizzle, tile widened to 128x256:
// 32 MFMA per K-step amortize the fixed per-step vmcnt(0) stall (2x work,
// same drain). LDS 48KB (As 2x8KB, Bs 2x16KB). Grid 384 = 32mt x 12nt.
__global__ __launch_bounds__(256, 2) void gemm_qkv(
    const ushort* __restrict__ A, const ushort* __restrict__ Bm,
    const float* __restrict__ bias, const float2* __restrict__ tab,
    ushort* __restrict__ Qb, ushort* __restrict__ Kb,
    ushort* __restrict__ Vsrc) {
  __shared__ __align__(16) char As[2][8192];    // 128 rows x 64 B
  __shared__ __align__(16) char Bs[2][16384];   // 256 rows x 64 B
  const int tid = threadIdx.x;
  const int w = tid >> 6, lane = tid & 63;

  // XCD swizzle: grid 384 = 32 mt x 12 nt, XCD region 8mt x 6nt
  const int bid = blockIdx.x;
  const int xcd = bid & 7, loc = bid >> 3;      // loc in [0,48)
  const int lm = loc & 7, ln = loc >> 3;        // 8 x 6
  const int mt = (xcd & 3) * 8 + lm;            // [0,32)
  const int ntile = (xcd >> 2) * 6 + ln;        // [0,12)
  const int m0 = mt * 128, n0 = ntile * 256;

  const int wm = (w >> 1) * 64, wn = (w & 1) * 128;  // wave: 64 x 128
  const int lrow = lane & 15, g = lane >> 4;
  const int swrd = (g ^ ((lrow >> 1) & 3)) << 4;  // read-side swizzled chunk

  // staging sources, pre-swizzled chunk' = (lane&3) ^ ((lane>>3)&3)
  // ((row>>1)&3 == (lane>>3)&3 for all staged rows: strides are mult of 16)
  const int swsrc = (((lane & 3) ^ ((lane >> 3) & 3)) << 4);
  const char* aG = (const char*)A + (size_t)(m0 + w * 32 + (lane >> 2)) * 2048 + swsrc;
  const char* bG = (const char*)Bm + (size_t)(n0 + w * 64 + (lane >> 2)) * 2048 + swsrc;
  const int ldstA = w * 2048 + lane * 16;   // + {0,1024}
  const int ldstB = w * 4096 + lane * 16;   // + t*1024, t=0..3

  auto STAGE = [&](const int buf) {
    gld_lds16(aG, &As[buf][0] + ldstA);
    gld_lds16(aG + 16 * 2048, &As[buf][0] + ldstA + 1024);
#pragma unroll
    for (int t = 0; t < 4; ++t)
      gld_lds16(bG + (size_t)t * 16 * 2048, &Bs[buf][0] + ldstB + t * 1024);
    aG += 64; bG += 64;  // advance K by 32 elements
  };

  floatx4 acc[4][8] = {};

  auto TILE = [&](const int buf) {
    short8 af[4], bf[8];
#pragma unroll
    for (int t = 0; t < 4; ++t)
      af[t] = *(const short8*)(&As[buf][0] + (wm + t * 16 + lrow) * 64 + swrd);
#pragma unroll
    for (int j = 0; j < 8; ++j)
      bf[j] = *(const short8*)(&Bs[buf][0] + (wn + j * 16 + lrow) * 64 + swrd);
#pragma unroll
    for (int i = 0; i < 4; ++i)
#pragma unroll
      for (int j = 0; j < 8; ++j)
        acc[i][j] = __builtin_amdgcn_mfma_f32_16x16x32_bf16(af[i], bf[j], acc[i][j], 0, 0, 0);
  };

  STAGE(0);
  asm volatile("s_waitcnt vmcnt(0)" ::: "memory");
  __builtin_amdgcn_s_barrier();
  __builtin_amdgcn_sched_barrier(0);

  for (int t = 0; t < 32; t += 2) {
    STAGE(1);
    __builtin_amdgcn_sched_barrier(0);
    TILE(0);
    asm volatile("s_waitcnt vmcnt(0)" ::: "memory");
    __builtin_amdgcn_s_barrier();
    __builtin_amdgcn_sched_barrier(0);

    if (t + 2 < 32) STAGE(0);
    __builtin_amdgcn_sched_barrier(0);
    TILE(1);
    asm volatile("s_waitcnt vmcnt(0)" ::: "memory");
    __builtin_amdgcn_s_barrier();
    __builtin_amdgcn_sched_barrier(0);
  }

  const int role = n0 >> 10;  // 256-strips never straddle q/k/v boundaries
  const float sc = (1.0f / 64.0f) * 1.44269504088896f;  // scale^2 * log2(e)
#pragma unroll
  for (int i = 0; i < 4; ++i) {
    int mrow = m0 + wm + i * 16 + (lane >> 4) * 4;
#pragma unroll
    for (int j = 0; j < 8; ++j) {
      int ncol = n0 + wn + j * 16 + (lane & 15);
      float bv = bias[ncol];
      int cm = ncol & 1023;
      int h = cm >> 6, d = cm & 63;
#pragma unroll
      for (int r = 0; r < 4; ++r) {
        float v = acc[i][j][r] + bv;
        int row = mrow + r;
        int b = row >> 10, n = row & 1023;
        if (role == 2) {
          Vsrc[(size_t)row * 1024 + cm] = f2bf(v);
        } else {
          float p = __shfl_xor(v, 1);  // partner col (d^1), same row
          float2 cs = tab[n * 32 + (d >> 1)];
          float o = (d & 1) ? (v * cs.x + p * cs.y) : (v * cs.x - p * cs.y);
          if (role == 0) o *= sc;
          ushort* dst = (role == 0) ? Qb : Kb;
          dst[((size_t)(b * 16 + h) * 1024 + n) * 64 + d] = f2bf(o);
        }
      }
    }
  }
}

// ---------------- GEMM2: out = AO @ proj_w^T + b (fp32 out) ----------------
// r12 3-stage counted pipeline + swizzled conflict-free reads. Grid 256.
__global__ __launch_bounds__(256, 3) void gemm_proj(
    const ushort* __restrict__ A, const ushort* __restrict__ Bm,
    const float* __restrict__ bias, float* __restrict__ Cout) {
  __shared__ __align__(16) char lds[3][16384];
  char* L0 = &lds[0][0];
  const int tid = threadIdx.x;
  const int w = tid >> 6, lane = tid & 63;

  const int bid = blockIdx.x;
  const int xcd = bid & 7, i5 = bid >> 3;
  const int lm = i5 & 7, ln = i5 >> 3;
  const int mt = (xcd & 3) * 8 + lm;
  const int nt = (xcd >> 2) * 4 + ln;
  const int m0 = mt * 128, n0 = nt * 128;

  const int wm = (w >> 1) * 64, wn = (w & 1) * 64;
  const int lrow = lane & 15, g = lane >> 4;
  const int swrd = (g ^ ((lrow >> 1) & 3)) << 4;

  const int swsrc = (((lane & 3) ^ ((lane >> 3) & 3)) << 4);
  const char* aG = (const char*)A + (size_t)(m0 + w * 32 + (lane >> 2)) * 2048 + swsrc;
  const char* bG = (const char*)Bm + (size_t)(n0 + w * 32 + (lane >> 2)) * 2048 + swsrc;
  const int ldst = w * 2048 + lane * 16;

  auto STAGE = [&](const int base) {
    char* L = L0 + base;
    gld_lds16(aG, L + ldst);
    gld_lds16(aG + 16 * 2048, L + ldst + 1024);
    gld_lds16(bG, L + 8192 + ldst);
    gld_lds16(bG + 16 * 2048, L + 8192 + ldst + 1024);
    aG += 64; bG += 64;
  };

  floatx4 acc[4][4] = {};

  auto TILE = [&](const int base) {
    const char* L = L0 + base;
    short8 af[4], bf[4];
#pragma unroll
    for (int t = 0; t < 4; ++t) {
      af[t] = *(const short8*)(L + (wm + t * 16 + lrow) * 64 + swrd);
      bf[t] = *(const short8*)(L + 8192 + (wn + t * 16 + lrow) * 64 + swrd);
    }
#pragma unroll
    for (int i = 0; i < 4; ++i)
#pragma unroll
      for (int j = 0; j < 4; ++j)
        acc[i][j] = __builtin_amdgcn_mfma_f32_16x16x32_bf16(af[i], bf[j], acc[i][j], 0, 0, 0);
  };

  STAGE(0);
  STAGE(16384);
  int bT = 0, bS = 32768;

  for (int t = 0; t < 31; ++t) {
    asm volatile("s_waitcnt vmcnt(4)" ::: "memory");
    __builtin_amdgcn_s_barrier();
    __builtin_amdgcn_sched_barrier(0);
    if (t < 30) STAGE(bS);
    __builtin_amdgcn_sched_barrier(0);
    TILE(bT);
    __builtin_amdgcn_sched_barrier(0);
    bT += 16384; if (bT == 49152) bT = 0;
    bS += 16384; if (bS == 49152) bS = 0;
  }
  asm volatile("s_waitcnt vmcnt(0)" ::: "memory");
  __builtin_amdgcn_s_barrier();
  __builtin_amdgcn_sched_barrier(0);
  TILE(bT);

#pragma unroll
  for (int i = 0; i < 4; ++i) {
    int mrow = m0 + wm + i * 16 + (lane >> 4) * 4;
#pragma unroll
    for (int j = 0; j < 4; ++j) {
      int ncol = n0 + wn + j * 16 + (lane & 15);
      float bv = bias[ncol];
#pragma unroll
      for (int r = 0; r < 4; ++r)
        Cout[(size_t)(mrow + r) * 1024 + ncol] = acc[i][j][r] + bv;
    }
  }
}

// ---------------- V transpose -> Vt (b,h,d,n) ----------------
__global__ __launch_bounds__(256, 4) void v_trans(
    const ushort* __restrict__ Vsrc, ushort* __restrict__ Vt) {
  __shared__ ushort t[64][72];
  int bh = blockIdx.y, ntile = blockIdx.x;
  int b = bh >> 4, h = bh & 15;
  int n0 = ntile * 64;
  int tid = threadIdx.x;
  int r = tid >> 2, cc = (tid & 3) * 16;
  const ushort* src = Vsrc + (size_t)(b * 1024 + n0 + r) * 1024 + h * 64 + cc;
  *(short8*)(&t[r][cc]) = *(const short8*)(src);
  *(short8*)(&t[r][cc + 8]) = *(const short8*)(src + 8);
  __syncthreads();
  int d = tid >> 2;
  ushort outv[16];
#pragma unroll
  for (int i = 0; i < 16; ++i) outv[i] = t[cc + i][d];
  ushort* dst = Vt + (size_t)bh * 65536 + (size_t)d * 1024 + n0 + cc;
  *(short8*)(dst) = *(const short8*)(outv);
  *(short8*)(dst + 8) = *(const short8*)(outv + 8);
}

// ---------------- Flash attention v5 (unchanged) ----------------
__global__ __launch_bounds__(256, 4) void attn(
    const ushort* __restrict__ Q, const ushort* __restrict__ Kc,
    const ushort* __restrict__ Vt, ushort* __restrict__ AO) {
  __shared__ char lds[2][16384];  // per buf: K tile 8KB @0, V tile 8KB @8192
  char* ldsbase = &lds[0][0];
  int id = blockIdx.x;
  int bh = id & 63, qi = id >> 6;
  int b = bh >> 4, h = bh & 15;
  int q0 = qi * 64;
  int tid = threadIdx.x, w = tid >> 6, lane = tid & 63;
  int l15 = lane & 15, g = lane >> 4;
  const ushort* Qbh = Q + (size_t)bh * 65536;
  const char* Kbh = (const char*)(Kc + (size_t)bh * 65536);
  const char* Vbh = (const char*)(Vt + (size_t)bh * 65536);

  short8 qf[2];
#pragma unroll
  for (int ks = 0; ks < 2; ++ks)
    qf[ks] = *(const short8*)(Qbh + (size_t)(q0 + w * 16 + l15) * 64 + ks * 32 + g * 8);

  int kaddr[8];
#pragma unroll
  for (int ks = 0; ks < 2; ++ks)
#pragma unroll
    for (int nt = 0; nt < 4; ++nt) {
      int row = nt * 16 + l15;
      kaddr[ks * 4 + nt] = (row * 128 + ks * 64 + g * 16) ^ ((row & 7) << 4);
    }
  int vaddr[16];
#pragma unroll
  for (int ch = 0; ch < 2; ++ch)
#pragma unroll
    for (int dt = 0; dt < 4; ++dt)
#pragma unroll
      for (int hf = 0; hf < 2; ++hf) {
        int row = dt * 16 + l15;
        vaddr[(ch * 4 + dt) * 2 + hf] =
            8192 + ((row * 128 + ch * 64 + hf * 32 + g * 8) ^ ((row & 7) << 4));
      }

  const int d0 = w * 2048 + lane * 16;
  const int d1 = d0 + 1024;
  const int r0 = d0 >> 7, r1 = d1 >> 7;
  const int s0 = d0 ^ ((r0 & 7) << 4), s1 = d1 ^ ((r1 & 7) << 4);
  const char* pK0 = Kbh + s0;
  const char* pK1 = Kbh + s1;
  const char* pV0 = Vbh + r0 * 2048 + (s0 & 127);
  const char* pV1 = Vbh + r1 * 2048 + (s1 & 127);

  auto STAGE = [&](const int B) {
    gld_lds16(pK0, ldsbase + B + d0);
    gld_lds16(pK1, ldsbase + B + d1);
    gld_lds16(pV0, ldsbase + B + 8192 + d0);
    gld_lds16(pV1, ldsbase + B + 8192 + d1);
    pK0 += 8192; pK1 += 8192; pV0 += 128; pV1 += 128;
  };

  floatx4 oacc[4] = {};
  float lrun = 0.f;

  auto TILE = [&](const int B) {
    floatx4 sacc[4] = {};
    __builtin_amdgcn_s_setprio(1);
#pragma unroll
    for (int ks = 0; ks < 2; ++ks) {
      short8 kf[4];
#pragma unroll
      for (int nt = 0; nt < 4; ++nt)
        kf[nt] = *(const short8*)(ldsbase + B + kaddr[ks * 4 + nt]);
#pragma unroll
      for (int nt = 0; nt < 4; ++nt)
        sacc[nt] = __builtin_amdgcn_mfma_f32_16x16x32_bf16(kf[nt], qf[ks], sacc[nt], 0, 0, 0);
    }
    __builtin_amdgcn_s_setprio(0);

    float rs = 0.f;
#pragma unroll
    for (int nt = 0; nt < 4; ++nt)
#pragma unroll
      for (int r = 0; r < 4; ++r) {
        float p = __builtin_amdgcn_exp2f(sacc[nt][r]);
        sacc[nt][r] = p;
        rs += p;
      }
    lrun += rs;

    short8 pa[2];
#pragma unroll
    for (int ch = 0; ch < 2; ++ch)
#pragma unroll
      for (int r = 0; r < 4; ++r) {
        pa[ch][r] = (short)f2bf_fast(sacc[2 * ch][r]);
        pa[ch][r + 4] = (short)f2bf_fast(sacc[2 * ch + 1][r]);
      }

    __builtin_amdgcn_s_setprio(1);
#pragma unroll
    for (int ch = 0; ch < 2; ++ch)
#pragma unroll
      for (int dt = 0; dt < 4; ++dt) {
        short4v va = *(const short4v*)(ldsbase + B + vaddr[(ch * 4 + dt) * 2]);
        short4v vb = *(const short4v*)(ldsbase + B + vaddr[(ch * 4 + dt) * 2 + 1]);
        short8 vf = __builtin_shufflevector(va, vb, 0, 1, 2, 3, 4, 5, 6, 7);
        oacc[dt] = __builtin_amdgcn_mfma_f32_16x16x32_bf16(pa[ch], vf, oacc[dt], 0, 0, 0);
      }
    __builtin_amdgcn_s_setprio(0);
  };

  STAGE(0);
  asm volatile("s_waitcnt vmcnt(0)" ::: "memory");
  __builtin_amdgcn_s_barrier();
  __builtin_amdgcn_sched_barrier(0);

  for (int kt = 0; kt < 16; kt += 2) {
    STAGE(16384);
    __builtin_amdgcn_sched_barrier(0);
    TILE(0);
    asm volatile("s_waitcnt vmcnt(0)" ::: "memory");
    __builtin_amdgcn_s_barrier();
    __builtin_amdgcn_sched_barrier(0);

    if (kt + 2 < 16) STAGE(0);
    __builtin_amdgcn_sched_barrier(0);
    TILE(16384);
    asm volatile("s_waitcnt vmcnt(0)" ::: "memory");
    __builtin_amdgcn_s_barrier();
    __builtin_amdgcn_sched_barrier(0);
  }

  lrun += __shfl_xor(lrun, 16);
  lrun += __shfl_xor(lrun, 32);
  float linv = 1.0f / lrun;
  float linvR[4];
#pragma unroll
  for (int r = 0; r < 4; ++r) linvR[r] = __shfl(linv, g * 4 + r);
#pragma unroll
  for (int r = 0; r < 4; ++r) {
    int nseq = q0 + w * 16 + g * 4 + r;
#pragma unroll
    for (int dt = 0; dt < 4; ++dt) {
      int d = dt * 16 + l15;
      AO[(size_t)(b * 1024 + nseq) * 1024 + h * 64 + d] = f2bf(oacc[dt][r] * linvR[r]);
    }
  }
}

extern "C" void kernel_launch(void* const* d_in, const int* in_sizes, int n_in,
                              void* d_out, int out_size, void* d_ws, size_t ws_size,
                              hipStream_t stream) {
  const float* x = (const float*)d_in[0];
  const float* qkv_w = (const float*)d_in[1];
  const float* qkv_b = (const float*)d_in[2];
  const float* proj_w = (const float*)d_in[3];
  const float* proj_b = (const float*)d_in[4];
  float* out = (float*)d_out;

  char* ws = (char*)d_ws;
  size_t off = 0;
  auto alloc = [&](size_t bytes) -> void* {
    void* p = ws + off;
    off += (bytes + 255) & ~(size_t)255;
    return p;
  };
  ushort* xb = (ushort*)alloc(4096ull * 1024 * 2);
  ushort* wqkvb = (ushort*)alloc(3072ull * 1024 * 2);
  ushort* wprojb = (ushort*)alloc(1024ull * 1024 * 2);
  ushort* Qb = (ushort*)alloc(64ull * 1024 * 64 * 2);
  ushort* Kb = (ushort*)alloc(64ull * 1024 * 64 * 2);
  ushort* Vsrc = (ushort*)alloc(4096ull * 1024 * 2);
  ushort* Vt = (ushort*)alloc(64ull * 1024 * 64 * 2);
  ushort* AO = (ushort*)alloc(4096ull * 1024 * 2);
  float2* tab = (float2*)alloc(1024ull * 32 * sizeof(float2));

  cast_all<<<2048, 256, 0, stream>>>(x, qkv_w, proj_w, xb, wqkvb, wprojb, tab);

  gemm_qkv<<<384, 256, 0, stream>>>(xb, wqkvb, qkv_b, tab, Qb, Kb, Vsrc);

  dim3 gv(16, 64);
  v_trans<<<gv, 256, 0, stream>>>(Vsrc, Vt);

  attn<<<1024, 256, 0, stream>>>(Qb, Kb, Vt, AO);

  gemm_proj<<<256, 256, 0, stream>>>(AO, wprojb, proj_b, out);
}

// Round 14
// 97.887 us; speedup vs baseline: 1.1500x; 1.1500x over previous
//
#include <hip/hip_runtime.h>
#include <hip/hip_bf16.h>
#include <stdint.h>

#define DEVI __device__ __forceinline__

typedef __attribute__((ext_vector_type(8))) short short8;
typedef __attribute__((ext_vector_type(4))) short short4v;
typedef __attribute__((ext_vector_type(4))) float floatx4;

DEVI ushort f2bf(float f) {
  union { float f; uint32_t u; } v; v.f = f;
  uint32_t u = v.u;
  uint32_t r = (u + 0x7FFFu + ((u >> 16) & 1u)) >> 16;
  return (ushort)r;
}
DEVI ushort f2bf_fast(float f) {
  union { float f; uint32_t u; } v; v.f = f;
  return (ushort)((v.u + 0x8000u) >> 16);
}
DEVI float bf2f(ushort h) {
  union { uint32_t u; float f; } v; v.u = ((uint32_t)h) << 16;
  return v.f;
}
DEVI void gld_lds16(const void* g, void* l) {
  __builtin_amdgcn_global_load_lds(
      (const __attribute__((address_space(1))) unsigned int*)g,
      (__attribute__((address_space(3))) unsigned int*)l, 16, 0, 0);
}

// ------- fused cast fp32 -> bf16 (x, qkv_w, proj_w) + RoPE table -------
__global__ __launch_bounds__(256, 4) void cast_all(
    const float* __restrict__ x, const float* __restrict__ w1,
    const float* __restrict__ w2, ushort* __restrict__ xb,
    ushort* __restrict__ w1b, ushort* __restrict__ w2b,
    float2* __restrict__ tab) {
  const int N1 = 4096 * 1024, N2 = 3072 * 1024, N3 = 1024 * 1024;
  int id = blockIdx.x * 256 + threadIdx.x;
  if (id < 32768) {  // RoPE cos/sin table: 1024 positions x 32 freq pairs
    int j = id & 31, n = id >> 5;
    float inv = powf(10000.0f, -(float)(2 * j) / 64.0f);
    float fr = (float)n * inv;
    tab[id] = make_float2(cosf(fr), sinf(fr));
  }
  int i = id * 4;
  const int total = N1 + N2 + N3;
  int stride = gridDim.x * 256 * 4;
  for (; i < total; i += stride) {
    const float* src; ushort* dst; int off;
    if (i < N1) { src = x; dst = xb; off = i; }
    else if (i < N1 + N2) { src = w1; dst = w1b; off = i - N1; }
    else { src = w2; dst = w2b; off = i - N1 - N2; }
    float4 v = *(const float4*)(src + off);
    ushort4 o;
    o.x = f2bf(v.x); o.y = f2bf(v.y); o.z = f2bf(v.z); o.w = f2bf(v.w);
    *(ushort4*)(dst + off) = o;
  }
}

// ---------------- GEMM1: qkv = x @ W^T + b, fused RoPE + scatter ----------
// r11 measured-best config: 2-phase dbuf (BK=32, 128^2 tile), conflict-free
// chunk swizzle c^=(row>>1)&3 (both-sides), (256,4), XCD swizzle, grid 768.
__global__ __launch_bounds__(256, 4) void gemm_qkv(
    const ushort* __restrict__ A, const ushort* __restrict__ Bm,
    const float* __restrict__ bias, const float2* __restrict__ tab,
    ushort* __restrict__ Qb, ushort* __restrict__ Kb,
    ushort* __restrict__ Vsrc) {
  __shared__ __align__(16) char As[2][8192];  // 128 rows x 64 B
  __shared__ __align__(16) char Bs[2][8192];
  const int tid = threadIdx.x;
  const int w = tid >> 6, lane = tid & 63;

  // XCD swizzle: grid 768 = 32 mt x 24 nt, XCD region 8mt x 12nt
  const int bid = blockIdx.x;
  const int xcd = bid & 7, i5 = bid >> 3;       // i5 in [0,96)
  const int lm = i5 & 7, ln = i5 >> 3;          // 8 x 12
  const int mt = (xcd & 3) * 8 + lm;            // [0,32)
  const int nt = (xcd >> 2) * 12 + ln;          // [0,24)
  const int m0 = mt * 128, n0 = nt * 128;

  const int wm = (w >> 1) * 64, wn = (w & 1) * 64;
  const int lrow = lane & 15, g = lane >> 4;
  const int swrd = (g ^ ((lrow >> 1) & 3)) << 4;  // read-side swizzled chunk

  // staging source pre-swizzled: chunk' = (lane&3) ^ ((lane>>3)&3)
  const int swsrc = (((lane & 3) ^ ((lane >> 3) & 3)) << 4);
  const char* aG = (const char*)A + (size_t)(m0 + w * 32 + (lane >> 2)) * 2048 + swsrc;
  const char* bG = (const char*)Bm + (size_t)(n0 + w * 32 + (lane >> 2)) * 2048 + swsrc;
  const int ldst = w * 2048 + lane * 16;

  auto STAGE = [&](const int buf) {
    gld_lds16(aG, &As[buf][0] + ldst);
    gld_lds16(aG + 16 * 2048, &As[buf][0] + ldst + 1024);
    gld_lds16(bG, &Bs[buf][0] + ldst);
    gld_lds16(bG + 16 * 2048, &Bs[buf][0] + ldst + 1024);
    aG += 64; bG += 64;  // advance K by 32 elements
  };

  floatx4 acc[4][4] = {};

  auto TILE = [&](const int buf) {
    short8 af[4], bf[4];
#pragma unroll
    for (int t = 0; t < 4; ++t) {
      af[t] = *(const short8*)(&As[buf][0] + (wm + t * 16 + lrow) * 64 + swrd);
      bf[t] = *(const short8*)(&Bs[buf][0] + (wn + t * 16 + lrow) * 64 + swrd);
    }
#pragma unroll
    for (int i = 0; i < 4; ++i)
#pragma unroll
      for (int j = 0; j < 4; ++j)
        acc[i][j] = __builtin_amdgcn_mfma_f32_16x16x32_bf16(af[i], bf[j], acc[i][j], 0, 0, 0);
  };

  STAGE(0);
  asm volatile("s_waitcnt vmcnt(0)" ::: "memory");
  __builtin_amdgcn_s_barrier();
  __builtin_amdgcn_sched_barrier(0);

  for (int t = 0; t < 32; t += 2) {
    STAGE(1);
    __builtin_amdgcn_sched_barrier(0);
    TILE(0);
    asm volatile("s_waitcnt vmcnt(0)" ::: "memory");
    __builtin_amdgcn_s_barrier();
    __builtin_amdgcn_sched_barrier(0);

    if (t + 2 < 32) STAGE(0);
    __builtin_amdgcn_sched_barrier(0);
    TILE(1);
    asm volatile("s_waitcnt vmcnt(0)" ::: "memory");
    __builtin_amdgcn_s_barrier();
    __builtin_amdgcn_sched_barrier(0);
  }

  const int role = n0 >> 10;  // 0=q, 1=k, 2=v (block cols never straddle)
  const float sc = (1.0f / 64.0f) * 1.44269504088896f;  // scale^2 * log2(e)
#pragma unroll
  for (int i = 0; i < 4; ++i) {
    int mrow = m0 + wm + i * 16 + (lane >> 4) * 4;
#pragma unroll
    for (int j = 0; j < 4; ++j) {
      int ncol = n0 + wn + j * 16 + (lane & 15);
      float bv = bias[ncol];
      int cm = ncol & 1023;
      int h = cm >> 6, d = cm & 63;
#pragma unroll
      for (int r = 0; r < 4; ++r) {
        float v = acc[i][j][r] + bv;
        int row = mrow + r;
        int b = row >> 10, n = row & 1023;
        if (role == 2) {
          Vsrc[(size_t)row * 1024 + cm] = f2bf(v);
        } else {
          float p = __shfl_xor(v, 1);  // partner col (d^1), same row
          float2 cs = tab[n * 32 + (d >> 1)];
          float o = (d & 1) ? (v * cs.x + p * cs.y) : (v * cs.x - p * cs.y);
          if (role == 0) o *= sc;
          ushort* dst = (role == 0) ? Qb : Kb;
          dst[((size_t)(b * 16 + h) * 1024 + n) * 64 + d] = f2bf(o);
        }
      }
    }
  }
}

// ---------------- GEMM2: out = AO @ proj_w^T + b (fp32 out) ----------------
// r12 3-stage counted pipeline + swizzled conflict-free reads. Grid 256.
__global__ __launch_bounds__(256, 3) void gemm_proj(
    const ushort* __restrict__ A, const ushort* __restrict__ Bm,
    const float* __restrict__ bias, float* __restrict__ Cout) {
  __shared__ __align__(16) char lds[3][16384];
  char* L0 = &lds[0][0];
  const int tid = threadIdx.x;
  const int w = tid >> 6, lane = tid & 63;

  const int bid = blockIdx.x;
  const int xcd = bid & 7, i5 = bid >> 3;
  const int lm = i5 & 7, ln = i5 >> 3;
  const int mt = (xcd & 3) * 8 + lm;
  const int nt = (xcd >> 2) * 4 + ln;
  const int m0 = mt * 128, n0 = nt * 128;

  const int wm = (w >> 1) * 64, wn = (w & 1) * 64;
  const int lrow = lane & 15, g = lane >> 4;
  const int swrd = (g ^ ((lrow >> 1) & 3)) << 4;

  const int swsrc = (((lane & 3) ^ ((lane >> 3) & 3)) << 4);
  const char* aG = (const char*)A + (size_t)(m0 + w * 32 + (lane >> 2)) * 2048 + swsrc;
  const char* bG = (const char*)Bm + (size_t)(n0 + w * 32 + (lane >> 2)) * 2048 + swsrc;
  const int ldst = w * 2048 + lane * 16;

  auto STAGE = [&](const int base) {
    char* L = L0 + base;
    gld_lds16(aG, L + ldst);
    gld_lds16(aG + 16 * 2048, L + ldst + 1024);
    gld_lds16(bG, L + 8192 + ldst);
    gld_lds16(bG + 16 * 2048, L + 8192 + ldst + 1024);
    aG += 64; bG += 64;
  };

  floatx4 acc[4][4] = {};

  auto TILE = [&](const int base) {
    const char* L = L0 + base;
    short8 af[4], bf[4];
#pragma unroll
    for (int t = 0; t < 4; ++t) {
      af[t] = *(const short8*)(L + (wm + t * 16 + lrow) * 64 + swrd);
      bf[t] = *(const short8*)(L + 8192 + (wn + t * 16 + lrow) * 64 + swrd);
    }
#pragma unroll
    for (int i = 0; i < 4; ++i)
#pragma unroll
      for (int j = 0; j < 4; ++j)
        acc[i][j] = __builtin_amdgcn_mfma_f32_16x16x32_bf16(af[i], bf[j], acc[i][j], 0, 0, 0);
  };

  STAGE(0);
  STAGE(16384);
  int bT = 0, bS = 32768;

  for (int t = 0; t < 31; ++t) {
    asm volatile("s_waitcnt vmcnt(4)" ::: "memory");
    __builtin_amdgcn_s_barrier();
    __builtin_amdgcn_sched_barrier(0);
    if (t < 30) STAGE(bS);
    __builtin_amdgcn_sched_barrier(0);
    TILE(bT);
    __builtin_amdgcn_sched_barrier(0);
    bT += 16384; if (bT == 49152) bT = 0;
    bS += 16384; if (bS == 49152) bS = 0;
  }
  asm volatile("s_waitcnt vmcnt(0)" ::: "memory");
  __builtin_amdgcn_s_barrier();
  __builtin_amdgcn_sched_barrier(0);
  TILE(bT);

#pragma unroll
  for (int i = 0; i < 4; ++i) {
    int mrow = m0 + wm + i * 16 + (lane >> 4) * 4;
#pragma unroll
    for (int j = 0; j < 4; ++j) {
      int ncol = n0 + wn + j * 16 + (lane & 15);
      float bv = bias[ncol];
#pragma unroll
      for (int r = 0; r < 4; ++r)
        Cout[(size_t)(mrow + r) * 1024 + ncol] = acc[i][j][r] + bv;
    }
  }
}

// ---------------- V transpose -> Vt (b,h,d,n) ----------------
__global__ __launch_bounds__(256, 4) void v_trans(
    const ushort* __restrict__ Vsrc, ushort* __restrict__ Vt) {
  __shared__ ushort t[64][72];
  int bh = blockIdx.y, ntile = blockIdx.x;
  int b = bh >> 4, h = bh & 15;
  int n0 = ntile * 64;
  int tid = threadIdx.x;
  int r = tid >> 2, cc = (tid & 3) * 16;
  const ushort* src = Vsrc + (size_t)(b * 1024 + n0 + r) * 1024 + h * 64 + cc;
  *(short8*)(&t[r][cc]) = *(const short8*)(src);
  *(short8*)(&t[r][cc + 8]) = *(const short8*)(src + 8);
  __syncthreads();
  int d = tid >> 2;
  ushort outv[16];
#pragma unroll
  for (int i = 0; i < 16; ++i) outv[i] = t[cc + i][d];
  ushort* dst = Vt + (size_t)bh * 65536 + (size_t)d * 1024 + n0 + cc;
  *(short8*)(dst) = *(const short8*)(outv);
  *(short8*)(dst + 8) = *(const short8*)(outv + 8);
}

// ---------------- Flash attention v5 (unchanged) ----------------
__global__ __launch_bounds__(256, 4) void attn(
    const ushort* __restrict__ Q, const ushort* __restrict__ Kc,
    const ushort* __restrict__ Vt, ushort* __restrict__ AO) {
  __shared__ char lds[2][16384];  // per buf: K tile 8KB @0, V tile 8KB @8192
  char* ldsbase = &lds[0][0];
  int id = blockIdx.x;
  int bh = id & 63, qi = id >> 6;
  int b = bh >> 4, h = bh & 15;
  int q0 = qi * 64;
  int tid = threadIdx.x, w = tid >> 6, lane = tid & 63;
  int l15 = lane & 15, g = lane >> 4;
  const ushort* Qbh = Q + (size_t)bh * 65536;
  const char* Kbh = (const char*)(Kc + (size_t)bh * 65536);
  const char* Vbh = (const char*)(Vt + (size_t)bh * 65536);

  short8 qf[2];
#pragma unroll
  for (int ks = 0; ks < 2; ++ks)
    qf[ks] = *(const short8*)(Qbh + (size_t)(q0 + w * 16 + l15) * 64 + ks * 32 + g * 8);

  int kaddr[8];
#pragma unroll
  for (int ks = 0; ks < 2; ++ks)
#pragma unroll
    for (int nt = 0; nt < 4; ++nt) {
      int row = nt * 16 + l15;
      kaddr[ks * 4 + nt] = (row * 128 + ks * 64 + g * 16) ^ ((row & 7) << 4);
    }
  int vaddr[16];
#pragma unroll
  for (int ch = 0; ch < 2; ++ch)
#pragma unroll
    for (int dt = 0; dt < 4; ++dt)
#pragma unroll
      for (int hf = 0; hf < 2; ++hf) {
        int row = dt * 16 + l15;
        vaddr[(ch * 4 + dt) * 2 + hf] =
            8192 + ((row * 128 + ch * 64 + hf * 32 + g * 8) ^ ((row & 7) << 4));
      }

  const int d0 = w * 2048 + lane * 16;
  const int d1 = d0 + 1024;
  const int r0 = d0 >> 7, r1 = d1 >> 7;
  const int s0 = d0 ^ ((r0 & 7) << 4), s1 = d1 ^ ((r1 & 7) << 4);
  const char* pK0 = Kbh + s0;
  const char* pK1 = Kbh + s1;
  const char* pV0 = Vbh + r0 * 2048 + (s0 & 127);
  const char* pV1 = Vbh + r1 * 2048 + (s1 & 127);

  auto STAGE = [&](const int B) {
    gld_lds16(pK0, ldsbase + B + d0);
    gld_lds16(pK1, ldsbase + B + d1);
    gld_lds16(pV0, ldsbase + B + 8192 + d0);
    gld_lds16(pV1, ldsbase + B + 8192 + d1);
    pK0 += 8192; pK1 += 8192; pV0 += 128; pV1 += 128;
  };

  floatx4 oacc[4] = {};
  float lrun = 0.f;

  auto TILE = [&](const int B) {
    floatx4 sacc[4] = {};
    __builtin_amdgcn_s_setprio(1);
#pragma unroll
    for (int ks = 0; ks < 2; ++ks) {
      short8 kf[4];
#pragma unroll
      for (int nt = 0; nt < 4; ++nt)
        kf[nt] = *(const short8*)(ldsbase + B + kaddr[ks * 4 + nt]);
#pragma unroll
      for (int nt = 0; nt < 4; ++nt)
        sacc[nt] = __builtin_amdgcn_mfma_f32_16x16x32_bf16(kf[nt], qf[ks], sacc[nt], 0, 0, 0);
    }
    __builtin_amdgcn_s_setprio(0);

    float rs = 0.f;
#pragma unroll
    for (int nt = 0; nt < 4; ++nt)
#pragma unroll
      for (int r = 0; r < 4; ++r) {
        float p = __builtin_amdgcn_exp2f(sacc[nt][r]);
        sacc[nt][r] = p;
        rs += p;
      }
    lrun += rs;

    short8 pa[2];
#pragma unroll
    for (int ch = 0; ch < 2; ++ch)
#pragma unroll
      for (int r = 0; r < 4; ++r) {
        pa[ch][r] = (short)f2bf_fast(sacc[2 * ch][r]);
        pa[ch][r + 4] = (short)f2bf_fast(sacc[2 * ch + 1][r]);
      }

    __builtin_amdgcn_s_setprio(1);
#pragma unroll
    for (int ch = 0; ch < 2; ++ch)
#pragma unroll
      for (int dt = 0; dt < 4; ++dt) {
        short4v va = *(const short4v*)(ldsbase + B + vaddr[(ch * 4 + dt) * 2]);
        short4v vb = *(const short4v*)(ldsbase + B + vaddr[(ch * 4 + dt) * 2 + 1]);
        short8 vf = __builtin_shufflevector(va, vb, 0, 1, 2, 3, 4, 5, 6, 7);
        oacc[dt] = __builtin_amdgcn_mfma_f32_16x16x32_bf16(pa[ch], vf, oacc[dt], 0, 0, 0);
      }
    __builtin_amdgcn_s_setprio(0);
  };

  STAGE(0);
  asm volatile("s_waitcnt vmcnt(0)" ::: "memory");
  __builtin_amdgcn_s_barrier();
  __builtin_amdgcn_sched_barrier(0);

  for (int kt = 0; kt < 16; kt += 2) {
    STAGE(16384);
    __builtin_amdgcn_sched_barrier(0);
    TILE(0);
    asm volatile("s_waitcnt vmcnt(0)" ::: "memory");
    __builtin_amdgcn_s_barrier();
    __builtin_amdgcn_sched_barrier(0);

    if (kt + 2 < 16) STAGE(0);
    __builtin_amdgcn_sched_barrier(0);
    TILE(16384);
    asm volatile("s_waitcnt vmcnt(0)" ::: "memory");
    __builtin_amdgcn_s_barrier();
    __builtin_amdgcn_sched_barrier(0);
  }

  lrun += __shfl_xor(lrun, 16);
  lrun += __shfl_xor(lrun, 32);
  float linv = 1.0f / lrun;
  float linvR[4];
#pragma unroll
  for (int r = 0; r < 4; ++r) linvR[r] = __shfl(linv, g * 4 + r);
#pragma unroll
  for (int r = 0; r < 4; ++r) {
    int nseq = q0 + w * 16 + g * 4 + r;
#pragma unroll
    for (int dt = 0; dt < 4; ++dt) {
      int d = dt * 16 + l15;
      AO[(size_t)(b * 1024 + nseq) * 1024 + h * 64 + d] = f2bf(oacc[dt][r] * linvR[r]);
    }
  }
}

extern "C" void kernel_launch(void* const* d_in, const int* in_sizes, int n_in,
                              void* d_out, int out_size, void* d_ws, size_t ws_size,
                              hipStream_t stream) {
  const float* x = (const float*)d_in[0];
  const float* qkv_w = (const float*)d_in[1];
  const float* qkv_b = (const float*)d_in[2];
  const float* proj_w = (const float*)d_in[3];
  const float* proj_b = (const float*)d_in[4];
  float* out = (float*)d_out;

  char* ws = (char*)d_ws;
  size_t off = 0;
  auto alloc = [&](size_t bytes) -> void* {
    void* p = ws + off;
    off += (bytes + 255) & ~(size_t)255;
    return p;
  };
  ushort* xb = (ushort*)alloc(4096ull * 1024 * 2);
  ushort* wqkvb = (ushort*)alloc(3072ull * 1024 * 2);
  ushort* wprojb = (ushort*)alloc(1024ull * 1024 * 2);
  ushort* Qb = (ushort*)alloc(64ull * 1024 * 64 * 2);
  ushort* Kb = (ushort*)alloc(64ull * 1024 * 64 * 2);
  ushort* Vsrc = (ushort*)alloc(4096ull * 1024 * 2);
  ushort* Vt = (ushort*)alloc(64ull * 1024 * 64 * 2);
  ushort* AO = (ushort*)alloc(4096ull * 1024 * 2);
  float2* tab = (float2*)alloc(1024ull * 32 * sizeof(float2));

  cast_all<<<2048, 256, 0, stream>>>(x, qkv_w, proj_w, xb, wqkvb, wprojb, tab);

  gemm_qkv<<<768, 256, 0, stream>>>(xb, wqkvb, qkv_b, tab, Qb, Kb, Vsrc);

  dim3 gv(16, 64);
  v_trans<<<gv, 256, 0, stream>>>(Vsrc, Vt);

  attn<<<1024, 256, 0, stream>>>(Qb, Kb, Vt, AO);

  gemm_proj<<<256, 256, 0, stream>>>(AO, wprojb, proj_b, out);
}

// Round 15
// 86.019 us; speedup vs baseline: 1.3087x; 1.1380x over previous
//
#include <hip/hip_runtime.h>
#include <hip/hip_bf16.h>
#include <stdint.h>

#define DEVI __device__ __forceinline__

typedef __attribute__((ext_vector_type(8))) short short8;
typedef __attribute__((ext_vector_type(4))) short short4v;
typedef __attribute__((ext_vector_type(4))) float floatx4;

DEVI ushort f2bf(float f) {
  union { float f; uint32_t u; } v; v.f = f;
  uint32_t u = v.u;
  uint32_t r = (u + 0x7FFFu + ((u >> 16) & 1u)) >> 16;
  return (ushort)r;
}
DEVI ushort f2bf_fast(float f) {
  union { float f; uint32_t u; } v; v.f = f;
  return (ushort)((v.u + 0x8000u) >> 16);
}
DEVI float bf2f(ushort h) {
  union { uint32_t u; float f; } v; v.u = ((uint32_t)h) << 16;
  return v.f;
}
DEVI void gld_lds16(const void* g, void* l) {
  __builtin_amdgcn_global_load_lds(
      (const __attribute__((address_space(1))) unsigned int*)g,
      (__attribute__((address_space(3))) unsigned int*)l, 16, 0, 0);
}

// ------- fused cast fp32 -> bf16 (x, qkv_w, proj_w) + RoPE table -------
__global__ __launch_bounds__(256, 4) void cast_all(
    const float* __restrict__ x, const float* __restrict__ w1,
    const float* __restrict__ w2, ushort* __restrict__ xb,
    ushort* __restrict__ w1b, ushort* __restrict__ w2b,
    float2* __restrict__ tab) {
  const int N1 = 4096 * 1024, N2 = 3072 * 1024, N3 = 1024 * 1024;
  int id = blockIdx.x * 256 + threadIdx.x;
  if (id < 32768) {  // RoPE cos/sin table: 1024 positions x 32 freq pairs
    int j = id & 31, n = id >> 5;
    float inv = powf(10000.0f, -(float)(2 * j) / 64.0f);
    float fr = (float)n * inv;
    tab[id] = make_float2(cosf(fr), sinf(fr));
  }
  int i = id * 4;
  const int total = N1 + N2 + N3;
  int stride = gridDim.x * 256 * 4;
  for (; i < total; i += stride) {
    const float* src; ushort* dst; int off;
    if (i < N1) { src = x; dst = xb; off = i; }
    else if (i < N1 + N2) { src = w1; dst = w1b; off = i - N1; }
    else { src = w2; dst = w2b; off = i - N1 - N2; }
    float4 v = *(const float4*)(src + off);
    ushort4 o;
    o.x = f2bf(v.x); o.y = f2bf(v.y); o.z = f2bf(v.z); o.w = f2bf(v.w);
    *(ushort4*)(dst + off) = o;
  }
}

// ---------------- GEMM1: qkv = x @ W^T + b, fused RoPE + scatter ----------
// r11/r14 measured-best K-loop (2-phase dbuf, BK=32, 128^2, conflict-free
// swizzle, (256,4), XCD swizzle, grid 768). NEW: role==2 (V) epilogue
// transposes through the (now-free) LDS pool and writes Vt directly —
// eliminates the v_trans kernel and the 16 MB Vsrc round-trip.
__global__ __launch_bounds__(256, 4) void gemm_qkv(
    const ushort* __restrict__ A, const ushort* __restrict__ Bm,
    const float* __restrict__ bias, const float2* __restrict__ tab,
    ushort* __restrict__ Qb, ushort* __restrict__ Kb,
    ushort* __restrict__ Vt) {
  __shared__ __align__(16) char pool[33792];  // K-loop: As/Bs 32KB; epi: T 33KB
  char* AsP = pool;            // [2][8192]: 128 rows x 64 B per buf
  char* BsP = pool + 16384;    // [2][8192]
  const int tid = threadIdx.x;
  const int w = tid >> 6, lane = tid & 63;

  // XCD swizzle: grid 768 = 32 mt x 24 nt, XCD region 8mt x 12nt
  const int bid = blockIdx.x;
  const int xcd = bid & 7, i5 = bid >> 3;       // i5 in [0,96)
  const int lm = i5 & 7, ln = i5 >> 3;          // 8 x 12
  const int mt = (xcd & 3) * 8 + lm;            // [0,32)
  const int nt = (xcd >> 2) * 12 + ln;          // [0,24)
  const int m0 = mt * 128, n0 = nt * 128;

  const int wm = (w >> 1) * 64, wn = (w & 1) * 64;
  const int lrow = lane & 15, g = lane >> 4;
  const int swrd = (g ^ ((lrow >> 1) & 3)) << 4;  // read-side swizzled chunk

  // staging source pre-swizzled: chunk' = (lane&3) ^ ((lane>>3)&3)
  const int swsrc = (((lane & 3) ^ ((lane >> 3) & 3)) << 4);
  const char* aG = (const char*)A + (size_t)(m0 + w * 32 + (lane >> 2)) * 2048 + swsrc;
  const char* bG = (const char*)Bm + (size_t)(n0 + w * 32 + (lane >> 2)) * 2048 + swsrc;
  const int ldst = w * 2048 + lane * 16;

  auto STAGE = [&](const int buf) {
    gld_lds16(aG, AsP + buf * 8192 + ldst);
    gld_lds16(aG + 16 * 2048, AsP + buf * 8192 + ldst + 1024);
    gld_lds16(bG, BsP + buf * 8192 + ldst);
    gld_lds16(bG + 16 * 2048, BsP + buf * 8192 + ldst + 1024);
    aG += 64; bG += 64;  // advance K by 32 elements
  };

  floatx4 acc[4][4] = {};

  auto TILE = [&](const int buf) {
    short8 af[4], bf[4];
#pragma unroll
    for (int t = 0; t < 4; ++t) {
      af[t] = *(const short8*)(AsP + buf * 8192 + (wm + t * 16 + lrow) * 64 + swrd);
      bf[t] = *(const short8*)(BsP + buf * 8192 + (wn + t * 16 + lrow) * 64 + swrd);
    }
#pragma unroll
    for (int i = 0; i < 4; ++i)
#pragma unroll
      for (int j = 0; j < 4; ++j)
        acc[i][j] = __builtin_amdgcn_mfma_f32_16x16x32_bf16(af[i], bf[j], acc[i][j], 0, 0, 0);
  };

  STAGE(0);
  asm volatile("s_waitcnt vmcnt(0)" ::: "memory");
  __builtin_amdgcn_s_barrier();
  __builtin_amdgcn_sched_barrier(0);

  for (int t = 0; t < 32; t += 2) {
    STAGE(1);
    __builtin_amdgcn_sched_barrier(0);
    TILE(0);
    asm volatile("s_waitcnt vmcnt(0)" ::: "memory");
    __builtin_amdgcn_s_barrier();
    __builtin_amdgcn_sched_barrier(0);

    if (t + 2 < 32) STAGE(0);
    __builtin_amdgcn_sched_barrier(0);
    TILE(1);
    asm volatile("s_waitcnt vmcnt(0)" ::: "memory");
    __builtin_amdgcn_s_barrier();
    __builtin_amdgcn_sched_barrier(0);
  }

  const int role = n0 >> 10;  // 0=q, 1=k, 2=v (block cols never straddle)
  if (role == 2) {
    // ---- V path: LDS transpose -> direct Vt (b,h,d,n) write ----
    // T[col][row]: row-pair stride 264 B (66 dwords: write banks 2-way-free,
    // 8B-granular reads ~4-way). K-loop's final barrier precedes reuse.
    char* T = pool;
#pragma unroll
    for (int i = 0; i < 4; ++i) {
      int lr0 = wm + i * 16 + g * 4;  // 4 consecutive local rows
#pragma unroll
      for (int j = 0; j < 4; ++j) {
        int lc = wn + j * 16 + lrow;
        float bv = bias[n0 + lc];
        ushort4 o;
#pragma unroll
        for (int r = 0; r < 4; ++r) ((ushort*)&o)[r] = f2bf(acc[i][j][r] + bv);
        *(ushort4*)(T + lc * 264 + lr0 * 2) = o;
      }
    }
    __syncthreads();
    const int b = m0 >> 10, nbase = m0 & 1023;
    const int h0 = (n0 - 2048) >> 6;
    const int c = tid >> 1, half = tid & 1;   // col 0..127, n-half 0..1
    const int h = h0 + (c >> 6), d = c & 63;
    ushort* dst = Vt + (size_t)(b * 16 + h) * 65536 + (size_t)d * 1024 + nbase + half * 64;
    const char* src = T + c * 264 + half * 128;
#pragma unroll
    for (int k = 0; k < 16; ++k)
      *(short4v*)(dst + k * 4) = *(const short4v*)(src + k * 8);
  } else {
    const float sc = (1.0f / 64.0f) * 1.44269504088896f;  // scale^2 * log2(e)
#pragma unroll
    for (int i = 0; i < 4; ++i) {
      int mrow = m0 + wm + i * 16 + g * 4;
#pragma unroll
      for (int j = 0; j < 4; ++j) {
        int ncol = n0 + wn + j * 16 + lrow;
        float bv = bias[ncol];
        int cm = ncol & 1023;
        int h = cm >> 6, d = cm & 63;
#pragma unroll
        for (int r = 0; r < 4; ++r) {
          float v = acc[i][j][r] + bv;
          int row = mrow + r;
          int b = row >> 10, n = row & 1023;
          float p = __shfl_xor(v, 1);  // partner col (d^1), same row
          float2 cs = tab[n * 32 + (d >> 1)];
          float o = (d & 1) ? (v * cs.x + p * cs.y) : (v * cs.x - p * cs.y);
          if (role == 0) o *= sc;
          ushort* dstqk = (role == 0) ? Qb : Kb;
          dstqk[((size_t)(b * 16 + h) * 1024 + n) * 64 + d] = f2bf(o);
        }
      }
    }
  }
}

// ---------------- GEMM2: out = AO @ proj_w^T + b (fp32 out) ----------------
// r12 3-stage counted pipeline + swizzled conflict-free reads. Grid 256.
__global__ __launch_bounds__(256, 3) void gemm_proj(
    const ushort* __restrict__ A, const ushort* __restrict__ Bm,
    const float* __restrict__ bias, float* __restrict__ Cout) {
  __shared__ __align__(16) char lds[3][16384];
  char* L0 = &lds[0][0];
  const int tid = threadIdx.x;
  const int w = tid >> 6, lane = tid & 63;

  const int bid = blockIdx.x;
  const int xcd = bid & 7, i5 = bid >> 3;
  const int lm = i5 & 7, ln = i5 >> 3;
  const int mt = (xcd & 3) * 8 + lm;
  const int nt = (xcd >> 2) * 4 + ln;
  const int m0 = mt * 128, n0 = nt * 128;

  const int wm = (w >> 1) * 64, wn = (w & 1) * 64;
  const int lrow = lane & 15, g = lane >> 4;
  const int swrd = (g ^ ((lrow >> 1) & 3)) << 4;

  const int swsrc = (((lane & 3) ^ ((lane >> 3) & 3)) << 4);
  const char* aG = (const char*)A + (size_t)(m0 + w * 32 + (lane >> 2)) * 2048 + swsrc;
  const char* bG = (const char*)Bm + (size_t)(n0 + w * 32 + (lane >> 2)) * 2048 + swsrc;
  const int ldst = w * 2048 + lane * 16;

  auto STAGE = [&](const int base) {
    char* L = L0 + base;
    gld_lds16(aG, L + ldst);
    gld_lds16(aG + 16 * 2048, L + ldst + 1024);
    gld_lds16(bG, L + 8192 + ldst);
    gld_lds16(bG + 16 * 2048, L + 8192 + ldst + 1024);
    aG += 64; bG += 64;
  };

  floatx4 acc[4][4] = {};

  auto TILE = [&](const int base) {
    const char* L = L0 + base;
    short8 af[4], bf[4];
#pragma unroll
    for (int t = 0; t < 4; ++t) {
      af[t] = *(const short8*)(L + (wm + t * 16 + lrow) * 64 + swrd);
      bf[t] = *(const short8*)(L + 8192 + (wn + t * 16 + lrow) * 64 + swrd);
    }
#pragma unroll
    for (int i = 0; i < 4; ++i)
#pragma unroll
      for (int j = 0; j < 4; ++j)
        acc[i][j] = __builtin_amdgcn_mfma_f32_16x16x32_bf16(af[i], bf[j], acc[i][j], 0, 0, 0);
  };

  STAGE(0);
  STAGE(16384);
  int bT = 0, bS = 32768;

  for (int t = 0; t < 31; ++t) {
    asm volatile("s_waitcnt vmcnt(4)" ::: "memory");
    __builtin_amdgcn_s_barrier();
    __builtin_amdgcn_sched_barrier(0);
    if (t < 30) STAGE(bS);
    __builtin_amdgcn_sched_barrier(0);
    TILE(bT);
    __builtin_amdgcn_sched_barrier(0);
    bT += 16384; if (bT == 49152) bT = 0;
    bS += 16384; if (bS == 49152) bS = 0;
  }
  asm volatile("s_waitcnt vmcnt(0)" ::: "memory");
  __builtin_amdgcn_s_barrier();
  __builtin_amdgcn_sched_barrier(0);
  TILE(bT);

#pragma unroll
  for (int i = 0; i < 4; ++i) {
    int mrow = m0 + wm + i * 16 + (lane >> 4) * 4;
#pragma unroll
    for (int j = 0; j < 4; ++j) {
      int ncol = n0 + wn + j * 16 + (lane & 15);
      float bv = bias[ncol];
#pragma unroll
      for (int r = 0; r < 4; ++r)
        Cout[(size_t)(mrow + r) * 1024 + ncol] = acc[i][j][r] + bv;
    }
  }
}

// ---------------- Flash attention v5 (unchanged) ----------------
__global__ __launch_bounds__(256, 4) void attn(
    const ushort* __restrict__ Q, const ushort* __restrict__ Kc,
    const ushort* __restrict__ Vt, ushort* __restrict__ AO) {
  __shared__ char lds[2][16384];  // per buf: K tile 8KB @0, V tile 8KB @8192
  char* ldsbase = &lds[0][0];
  int id = blockIdx.x;
  int bh = id & 63, qi = id >> 6;
  int b = bh >> 4, h = bh & 15;
  int q0 = qi * 64;
  int tid = threadIdx.x, w = tid >> 6, lane = tid & 63;
  int l15 = lane & 15, g = lane >> 4;
  const ushort* Qbh = Q + (size_t)bh * 65536;
  const char* Kbh = (const char*)(Kc + (size_t)bh * 65536);
  const char* Vbh = (const char*)(Vt + (size_t)bh * 65536);

  short8 qf[2];
#pragma unroll
  for (int ks = 0; ks < 2; ++ks)
    qf[ks] = *(const short8*)(Qbh + (size_t)(q0 + w * 16 + l15) * 64 + ks * 32 + g * 8);

  int kaddr[8];
#pragma unroll
  for (int ks = 0; ks < 2; ++ks)
#pragma unroll
    for (int nt = 0; nt < 4; ++nt) {
      int row = nt * 16 + l15;
      kaddr[ks * 4 + nt] = (row * 128 + ks * 64 + g * 16) ^ ((row & 7) << 4);
    }
  int vaddr[16];
#pragma unroll
  for (int ch = 0; ch < 2; ++ch)
#pragma unroll
    for (int dt = 0; dt < 4; ++dt)
#pragma unroll
      for (int hf = 0; hf < 2; ++hf) {
        int row = dt * 16 + l15;
        vaddr[(ch * 4 + dt) * 2 + hf] =
            8192 + ((row * 128 + ch * 64 + hf * 32 + g * 8) ^ ((row & 7) << 4));
      }

  const int d0 = w * 2048 + lane * 16;
  const int d1 = d0 + 1024;
  const int r0 = d0 >> 7, r1 = d1 >> 7;
  const int s0 = d0 ^ ((r0 & 7) << 4), s1 = d1 ^ ((r1 & 7) << 4);
  const char* pK0 = Kbh + s0;
  const char* pK1 = Kbh + s1;
  const char* pV0 = Vbh + r0 * 2048 + (s0 & 127);
  const char* pV1 = Vbh + r1 * 2048 + (s1 & 127);

  auto STAGE = [&](const int B) {
    gld_lds16(pK0, ldsbase + B + d0);
    gld_lds16(pK1, ldsbase + B + d1);
    gld_lds16(pV0, ldsbase + B + 8192 + d0);
    gld_lds16(pV1, ldsbase + B + 8192 + d1);
    pK0 += 8192; pK1 += 8192; pV0 += 128; pV1 += 128;
  };

  floatx4 oacc[4] = {};
  float lrun = 0.f;

  auto TILE = [&](const int B) {
    floatx4 sacc[4] = {};
    __builtin_amdgcn_s_setprio(1);
#pragma unroll
    for (int ks = 0; ks < 2; ++ks) {
      short8 kf[4];
#pragma unroll
      for (int nt = 0; nt < 4; ++nt)
        kf[nt] = *(const short8*)(ldsbase + B + kaddr[ks * 4 + nt]);
#pragma unroll
      for (int nt = 0; nt < 4; ++nt)
        sacc[nt] = __builtin_amdgcn_mfma_f32_16x16x32_bf16(kf[nt], qf[ks], sacc[nt], 0, 0, 0);
    }
    __builtin_amdgcn_s_setprio(0);

    float rs = 0.f;
#pragma unroll
    for (int nt = 0; nt < 4; ++nt)
#pragma unroll
      for (int r = 0; r < 4; ++r) {
        float p = __builtin_amdgcn_exp2f(sacc[nt][r]);
        sacc[nt][r] = p;
        rs += p;
      }
    lrun += rs;

    short8 pa[2];
#pragma unroll
    for (int ch = 0; ch < 2; ++ch)
#pragma unroll
      for (int r = 0; r < 4; ++r) {
        pa[ch][r] = (short)f2bf_fast(sacc[2 * ch][r]);
        pa[ch][r + 4] = (short)f2bf_fast(sacc[2 * ch + 1][r]);
      }

    __builtin_amdgcn_s_setprio(1);
#pragma unroll
    for (int ch = 0; ch < 2; ++ch)
#pragma unroll
      for (int dt = 0; dt < 4; ++dt) {
        short4v va = *(const short4v*)(ldsbase + B + vaddr[(ch * 4 + dt) * 2]);
        short4v vb = *(const short4v*)(ldsbase + B + vaddr[(ch * 4 + dt) * 2 + 1]);
        short8 vf = __builtin_shufflevector(va, vb, 0, 1, 2, 3, 4, 5, 6, 7);
        oacc[dt] = __builtin_amdgcn_mfma_f32_16x16x32_bf16(pa[ch], vf, oacc[dt], 0, 0, 0);
      }
    __builtin_amdgcn_s_setprio(0);
  };

  STAGE(0);
  asm volatile("s_waitcnt vmcnt(0)" ::: "memory");
  __builtin_amdgcn_s_barrier();
  __builtin_amdgcn_sched_barrier(0);

  for (int kt = 0; kt < 16; kt += 2) {
    STAGE(16384);
    __builtin_amdgcn_sched_barrier(0);
    TILE(0);
    asm volatile("s_waitcnt vmcnt(0)" ::: "memory");
    __builtin_amdgcn_s_barrier();
    __builtin_amdgcn_sched_barrier(0);

    if (kt + 2 < 16) STAGE(0);
    __builtin_amdgcn_sched_barrier(0);
    TILE(16384);
    asm volatile("s_waitcnt vmcnt(0)" ::: "memory");
    __builtin_amdgcn_s_barrier();
    __builtin_amdgcn_sched_barrier(0);
  }

  lrun += __shfl_xor(lrun, 16);
  lrun += __shfl_xor(lrun, 32);
  float linv = 1.0f / lrun;
  float linvR[4];
#pragma unroll
  for (int r = 0; r < 4; ++r) linvR[r] = __shfl(linv, g * 4 + r);
#pragma unroll
  for (int r = 0; r < 4; ++r) {
    int nseq = q0 + w * 16 + g * 4 + r;
#pragma unroll
    for (int dt = 0; dt < 4; ++dt) {
      int d = dt * 16 + l15;
      AO[(size_t)(b * 1024 + nseq) * 1024 + h * 64 + d] = f2bf(oacc[dt][r] * linvR[r]);
    }
  }
}

extern "C" void kernel_launch(void* const* d_in, const int* in_sizes, int n_in,
                              void* d_out, int out_size, void* d_ws, size_t ws_size,
                              hipStream_t stream) {
  const float* x = (const float*)d_in[0];
  const float* qkv_w = (const float*)d_in[1];
  const float* qkv_b = (const float*)d_in[2];
  const float* proj_w = (const float*)d_in[3];
  const float* proj_b = (const float*)d_in[4];
  float* out = (float*)d_out;

  char* ws = (char*)d_ws;
  size_t off = 0;
  auto alloc = [&](size_t bytes) -> void* {
    void* p = ws + off;
    off += (bytes + 255) & ~(size_t)255;
    return p;
  };
  ushort* xb = (ushort*)alloc(4096ull * 1024 * 2);
  ushort* wqkvb = (ushort*)alloc(3072ull * 1024 * 2);
  ushort* wprojb = (ushort*)alloc(1024ull * 1024 * 2);
  ushort* Qb = (ushort*)alloc(64ull * 1024 * 64 * 2);
  ushort* Kb = (ushort*)alloc(64ull * 1024 * 64 * 2);
  ushort* Vt = (ushort*)alloc(64ull * 1024 * 64 * 2);
  ushort* AO = (ushort*)alloc(4096ull * 1024 * 2);
  float2* tab = (float2*)alloc(1024ull * 32 * sizeof(float2));

  cast_all<<<2048, 256, 0, stream>>>(x, qkv_w, proj_w, xb, wqkvb, wprojb, tab);

  gemm_qkv<<<768, 256, 0, stream>>>(xb, wqkvb, qkv_b, tab, Qb, Kb, Vt);

  attn<<<1024, 256, 0, stream>>>(Qb, Kb, Vt, AO);

  gemm_proj<<<256, 256, 0, stream>>>(AO, wprojb, proj_b, out);
}